// Round 1
// baseline (16824.796 us; speedup 1.0000x reference)
//
#include <hip/hip_runtime.h>
#include <cstdint>
#include <cstddef>

#define Tn 4096
#define Bn 64
#define Hn 256
#define En 256
#define Vn 50257
#define D2H 512   // 2H
#define K3H 768   // 3H

// ---------------------------------------------------------------------------
// ws layout (float offsets):
//   baseT : [0, 16384)        (256h x 64b)   b_attn + W1 @ h0  (transposed)
//   emb_g : [16384, 32768)    (64b x 256e)   gathered embeddings
//   attn  : [32768, 294912)   (4096t x 64b)  scores -> softmax weights
//   part  : [294912, 2392064) (64tc x 64b x 512d) context partials
//   y     : [2392064, 2441216)(64b x 768)    [h_new(256) | ctx(512)]
// total ~9.77 MB
// ---------------------------------------------------------------------------

// K1: embedding gather + base[b][h] = b_attn[h] + W_attn[h][0:256] . h0[b]
__global__ __launch_bounds__(256) void k1_embed_base(
    const int* __restrict__ ids, const float* __restrict__ hidden,
    const float* __restrict__ emb, const float* __restrict__ W_attn,
    const float* __restrict__ b_attn,
    float* __restrict__ baseT, float* __restrict__ emb_g)
{
    const int b = blockIdx.x, h = threadIdx.x;
    __shared__ float h0[Hn];
    h0[h] = hidden[b * Hn + h];
    __syncthreads();
    float acc = b_attn[h];
    const float* wrow = W_attn + (size_t)h * K3H;
#pragma unroll 8
    for (int k = 0; k < Hn; ++k) acc += wrow[k] * h0[k];
    baseT[h * Bn + b] = acc;                 // transposed for coalesced K2 reads
    const int id = ids[b];
    emb_g[b * En + h] = emb[(size_t)id * En + h];
}

// K2: scores[t][b] = v . tanh(base[b] + W2 @ enc[t][b])
// block = one t, 1024 threads: lane (0..63) = b, wave (0..15) owns 16 h's.
__global__ __launch_bounds__(1024) void k2_scores(
    const float* __restrict__ enc, const float* __restrict__ W_attn,
    const float* __restrict__ vvec, const float* __restrict__ baseT,
    float* __restrict__ scores)
{
    const int t = blockIdx.x;
    const int lane = threadIdx.x & 63;   // b
    const int wave = threadIdx.x >> 6;   // h = wave*16 + hh
    __shared__ float lds_e[64][68];      // enc chunk [b][k], padded (bank-safe)
    __shared__ float red[16][64];

    float acc[16];
#pragma unroll
    for (int hh = 0; hh < 16; ++hh)
        acc[hh] = baseT[(wave * 16 + hh) * Bn + lane];   // coalesced

    const float* encT = enc + (size_t)t * (Bn * D2H);

    for (int kc = 0; kc < 8; ++kc) {     // 8 chunks of 64 k
        __syncthreads();
#pragma unroll
        for (int u = 0; u < 4; ++u) {
            int idx = threadIdx.x + u * 1024;            // 0..4095
            int bb = idx >> 6, kk = idx & 63;
            lds_e[bb][kk] = encT[bb * D2H + kc * 64 + kk]; // coalesced global
        }
        __syncthreads();

        float4 er[16];                    // this thread's b-row, 64 k as float4
#pragma unroll
        for (int j = 0; j < 16; ++j)
            er[j] = *reinterpret_cast<const float4*>(&lds_e[lane][j * 4]);

#pragma unroll
        for (int hh = 0; hh < 16; ++hh) {
            // W2 row: broadcast (wave-uniform) loads, L2-resident (768 KB total)
            const float4* wrow = reinterpret_cast<const float4*>(
                W_attn + (size_t)(wave * 16 + hh) * K3H + Hn + kc * 64);
            float a = acc[hh];
#pragma unroll
            for (int j = 0; j < 16; ++j) {
                float4 w = wrow[j];
                a += w.x * er[j].x + w.y * er[j].y + w.z * er[j].z + w.w * er[j].w;
            }
            acc[hh] = a;
        }
    }

    // epilogue: score partial = sum_h v[h]*tanh(acc[h]); reduce across 16 waves
    float sp = 0.f;
#pragma unroll
    for (int hh = 0; hh < 16; ++hh)
        sp += vvec[wave * 16 + hh] * tanhf(acc[hh]);
    red[wave][lane] = sp;
    __syncthreads();
    if (threadIdx.x < 64) {
        float s = 0.f;
#pragma unroll
        for (int w = 0; w < 16; ++w) s += red[w][threadIdx.x];
        scores[(size_t)t * Bn + threadIdx.x] = s;
    }
}

// K3: in-place softmax over t (axis 0) for each b
__global__ __launch_bounds__(1024) void k3_softmax(float* __restrict__ sc)
{
    const int b = blockIdx.x;
    __shared__ float red[1024];
    float m = -1e30f;
    for (int t = threadIdx.x; t < Tn; t += 1024) m = fmaxf(m, sc[(size_t)t * Bn + b]);
    red[threadIdx.x] = m; __syncthreads();
    for (int s = 512; s > 0; s >>= 1) {
        if (threadIdx.x < s) red[threadIdx.x] = fmaxf(red[threadIdx.x], red[threadIdx.x + s]);
        __syncthreads();
    }
    m = red[0]; __syncthreads();
    float l = 0.f;
    for (int t = threadIdx.x; t < Tn; t += 1024) l += expf(sc[(size_t)t * Bn + b] - m);
    red[threadIdx.x] = l; __syncthreads();
    for (int s = 512; s > 0; s >>= 1) {
        if (threadIdx.x < s) red[threadIdx.x] += red[threadIdx.x + s];
        __syncthreads();
    }
    l = red[0];
    const float inv = 1.0f / l;
    for (int t = threadIdx.x; t < Tn; t += 1024) {
        size_t i = (size_t)t * Bn + b;
        sc[i] = expf(sc[i] - m) * inv;
    }
}

// K4: context partials: part[tc][b][d] = sum_{t in chunk} attn[t][b]*enc[t][b][d]
__global__ __launch_bounds__(256) void k4_ctx_part(
    const float* __restrict__ enc, const float* __restrict__ attn,
    float* __restrict__ part)
{
    const int tc = blockIdx.x, b = blockIdx.y, d = threadIdx.x;
    float c0 = 0.f, c1 = 0.f;
    for (int tt = 0; tt < 64; ++tt) {
        const int t = tc * 64 + tt;
        const float w = attn[(size_t)t * Bn + b];
        const float* e = enc + (size_t)t * (Bn * D2H) + b * D2H;
        c0 += w * e[d];
        c1 += w * e[d + 256];
    }
    float* p = part + ((size_t)tc * Bn + b) * D2H;
    p[d] = c0; p[d + 256] = c1;
}

// K5: reduce partials -> ctx, written into y[b][256: 768]
__global__ __launch_bounds__(256) void k5_ctx_reduce(
    const float* __restrict__ part, float* __restrict__ y)
{
    const int b = blockIdx.x, d = threadIdx.x;
    float c0 = 0.f, c1 = 0.f;
    for (int tc = 0; tc < 64; ++tc) {
        const float* p = part + ((size_t)tc * Bn + b) * D2H;
        c0 += p[d]; c1 += p[d + 256];
    }
    y[(size_t)b * K3H + Hn + d] = c0;
    y[(size_t)b * K3H + Hn + 256 + d] = c1;
}

// K6: comb = W_comb @ [ctx, emb] + b_comb; GRU step -> h_new into y[b][0:256]
// and into d_out tail
__global__ __launch_bounds__(256) void k6_gru(
    const float* __restrict__ hidden, const float* __restrict__ emb_g,
    const float* __restrict__ W_comb, const float* __restrict__ b_comb,
    const float* __restrict__ W_ih, const float* __restrict__ W_hh,
    const float* __restrict__ b_ih, const float* __restrict__ b_hh,
    float* __restrict__ y, float* __restrict__ out_hidden)
{
    const int b = blockIdx.x, h = threadIdx.x;
    __shared__ float in_[K3H];   // [ctx(512) | emb(256)]
    __shared__ float h0[Hn];
    __shared__ float comb[Hn];
    __shared__ float gx[K3H], gh[K3H];
    in_[h]       = y[(size_t)b * K3H + Hn + h];
    in_[256 + h] = y[(size_t)b * K3H + Hn + 256 + h];
    in_[512 + h] = emb_g[b * En + h];
    h0[h] = hidden[b * Hn + h];
    __syncthreads();
    {
        float c = b_comb[h];
        const float* wr = W_comb + (size_t)h * K3H;
#pragma unroll 8
        for (int k = 0; k < K3H; ++k) c += wr[k] * in_[k];
        comb[h] = c;
    }
    __syncthreads();
#pragma unroll
    for (int p = 0; p < 3; ++p) {
        const int g = p * 256 + h;
        float a = b_ih[g], bh = b_hh[g];
        const float* wi = W_ih + (size_t)g * Hn;
        const float* wh = W_hh + (size_t)g * Hn;
#pragma unroll 8
        for (int k = 0; k < Hn; ++k) { a += wi[k] * comb[k]; bh += wh[k] * h0[k]; }
        gx[g] = a; gh[g] = bh;
    }
    __syncthreads();
    const float r = 1.f / (1.f + expf(-(gx[h] + gh[h])));
    const float z = 1.f / (1.f + expf(-(gx[256 + h] + gh[256 + h])));
    const float n = tanhf(gx[512 + h] + r * gh[512 + h]);
    const float hn = (1.f - z) * n + z * h0[h];
    y[(size_t)b * K3H + h] = hn;
    out_hidden[b * Hn + h] = hn;
}

// K7: logits[b][v] = b_out[v] + W_out[v] . y[b]; tiled 64v x 64b per block
__global__ __launch_bounds__(256) void k7_logits(
    const float* __restrict__ W_out, const float* __restrict__ b_out,
    const float* __restrict__ y, float* __restrict__ out)
{
    const int vbase = blockIdx.x * 64;
    const int tv = threadIdx.x & 15;   // v quad -> v = vbase + tv*4 + i
    const int tb = threadIdx.x >> 4;   // b quad -> b = tb*4 + j
    __shared__ float lw[64][33];
    __shared__ float ly[32][68];
    float acc[4][4] = {};
    for (int kc = 0; kc < 24; ++kc) {  // 24 chunks of 32 k
        __syncthreads();
#pragma unroll
        for (int u = 0; u < 8; ++u) {
            int idx = threadIdx.x + u * 256;       // 0..2047
            int r = idx >> 5, c = idx & 31;
            int vv = vbase + r;
            lw[r][c] = (vv < Vn) ? W_out[(size_t)vv * K3H + kc * 32 + c] : 0.f;
        }
#pragma unroll
        for (int u = 0; u < 8; ++u) {
            int idx = threadIdx.x + u * 256;
            int k = idx >> 6, bb = idx & 63;
            ly[k][bb] = y[(size_t)bb * K3H + kc * 32 + k];
        }
        __syncthreads();
        for (int k = 0; k < 32; ++k) {
            float wv[4], yv[4];
#pragma unroll
            for (int i = 0; i < 4; ++i) wv[i] = lw[tv * 4 + i][k];
#pragma unroll
            for (int j = 0; j < 4; ++j) yv[j] = ly[k][tb * 4 + j];
#pragma unroll
            for (int i = 0; i < 4; ++i)
#pragma unroll
                for (int j = 0; j < 4; ++j) acc[i][j] += wv[i] * yv[j];
        }
    }
#pragma unroll
    for (int i = 0; i < 4; ++i) {
        const int vv = vbase + tv * 4 + i;
        if (vv < Vn) {
            const float bo = b_out[vv];
#pragma unroll
            for (int j = 0; j < 4; ++j) {
                const int b = tb * 4 + j;
                out[(size_t)b * Vn + vv] = acc[i][j] + bo;
            }
        }
    }
}

// K8: in-place log_softmax over V per row b
__global__ __launch_bounds__(1024) void k8_logsoftmax(float* __restrict__ out)
{
    const int b = blockIdx.x;
    float* row = out + (size_t)b * Vn;
    __shared__ float red[1024];
    float m = -1e30f;
    for (int i = threadIdx.x; i < Vn; i += 1024) m = fmaxf(m, row[i]);
    red[threadIdx.x] = m; __syncthreads();
    for (int s = 512; s > 0; s >>= 1) {
        if (threadIdx.x < s) red[threadIdx.x] = fmaxf(red[threadIdx.x], red[threadIdx.x + s]);
        __syncthreads();
    }
    m = red[0]; __syncthreads();
    float l = 0.f;
    for (int i = threadIdx.x; i < Vn; i += 1024) l += expf(row[i] - m);
    red[threadIdx.x] = l; __syncthreads();
    for (int s = 512; s > 0; s >>= 1) {
        if (threadIdx.x < s) red[threadIdx.x] += red[threadIdx.x + s];
        __syncthreads();
    }
    l = red[0];
    const float off = m + logf(l);
    for (int i = threadIdx.x; i < Vn; i += 1024) row[i] = row[i] - off;
}

extern "C" void kernel_launch(void* const* d_in, const int* in_sizes, int n_in,
                              void* d_out, int out_size, void* d_ws, size_t ws_size,
                              hipStream_t stream)
{
    const int*   ids    = (const int*)d_in[0];
    const float* hidden = (const float*)d_in[1];
    const float* enc    = (const float*)d_in[2];
    const float* emb    = (const float*)d_in[3];
    const float* W_attn = (const float*)d_in[4];
    const float* b_attn = (const float*)d_in[5];
    const float* vvec   = (const float*)d_in[6];
    const float* W_comb = (const float*)d_in[7];
    const float* b_comb = (const float*)d_in[8];
    const float* W_ih   = (const float*)d_in[9];
    const float* W_hh   = (const float*)d_in[10];
    const float* b_ih   = (const float*)d_in[11];
    const float* b_hh   = (const float*)d_in[12];
    const float* W_out  = (const float*)d_in[13];
    const float* b_out  = (const float*)d_in[14];

    float* out = (float*)d_out;
    float* ws = (float*)d_ws;
    float* baseT = ws;                  // 16384
    float* emb_g = ws + 16384;          // 16384
    float* attn  = ws + 32768;          // 262144
    float* part  = ws + 294912;         // 2097152
    float* y     = ws + 2392064;        // 49152

    hipLaunchKernelGGL(k1_embed_base, dim3(Bn), dim3(256), 0, stream,
                       ids, hidden, emb, W_attn, b_attn, baseT, emb_g);
    hipLaunchKernelGGL(k2_scores, dim3(Tn), dim3(1024), 0, stream,
                       enc, W_attn, vvec, baseT, attn);
    hipLaunchKernelGGL(k3_softmax, dim3(Bn), dim3(1024), 0, stream, attn);
    hipLaunchKernelGGL(k4_ctx_part, dim3(64, Bn), dim3(256), 0, stream,
                       enc, attn, part);
    hipLaunchKernelGGL(k5_ctx_reduce, dim3(Bn), dim3(256), 0, stream, part, y);
    hipLaunchKernelGGL(k6_gru, dim3(Bn), dim3(256), 0, stream,
                       hidden, emb_g, W_comb, b_comb, W_ih, W_hh, b_ih, b_hh,
                       y, out + (size_t)Bn * Vn);
    hipLaunchKernelGGL(k7_logits, dim3((Vn + 63) / 64), dim3(256), 0, stream,
                       W_out, b_out, y, out);
    hipLaunchKernelGGL(k8_logsoftmax, dim3(Bn), dim3(1024), 0, stream, out);
}

// Round 2
// 801.585 us; speedup vs baseline: 20.9894x; 20.9894x over previous
//
#include <hip/hip_runtime.h>
#include <cstdint>
#include <cstddef>

#define Tn 4096
#define Bn 64
#define Hn 256
#define En 256
#define Vn 50257
#define D2H 512   // 2H
#define K3H 768   // 3H

typedef __attribute__((ext_vector_type(8))) short short8;
typedef __attribute__((ext_vector_type(4))) float f32x4;

// f32 -> bf16 round-to-nearest-even
__device__ __forceinline__ unsigned short f2bf(float f)
{
    union { float f; unsigned int u; } v; v.f = f;
    unsigned int u = v.u;
    return (unsigned short)((u + 0x7fffu + ((u >> 16) & 1u)) >> 16);
}

// ---------------------------------------------------------------------------
// ws layout (float offsets):
//   baseT  : [0, 16384)          (256h x 64b)  b_attn + W1 @ h0 (transposed)
//   emb_g  : [16384, 32768)      (64b x 256e)
//   attn   : [32768, 294912)     (4096t x 64b) scores -> softmax weights
//   part   : [294912, 1343488)   (32tc x 64b x 512d) context partials
//   y      : [1343488, 1392640)  (64b x 768)  [h_new(256) | ctx(512)]
//   w2frag : [1392640, 1458176)  256 KB bf16: W2 in MFMA B-fragment layout
// total ~5.83 MB
// ---------------------------------------------------------------------------

// K1: embedding gather + base[b][h] = b_attn[h] + W_attn[h][0:256] . h0[b]
__global__ __launch_bounds__(256) void k1_embed_base(
    const int* __restrict__ ids, const float* __restrict__ hidden,
    const float* __restrict__ emb, const float* __restrict__ W_attn,
    const float* __restrict__ b_attn,
    float* __restrict__ baseT, float* __restrict__ emb_g)
{
    const int b = blockIdx.x, h = threadIdx.x;
    __shared__ float h0[Hn];
    h0[h] = hidden[b * Hn + h];
    __syncthreads();
    float acc = b_attn[h];
    const float* wrow = W_attn + (size_t)h * K3H;
#pragma unroll 8
    for (int k = 0; k < Hn; ++k) acc += wrow[k] * h0[k];
    baseT[h * Bn + b] = acc;
    const int id = ids[b];
    emb_g[b * En + h] = emb[(size_t)id * En + h];
}

// K1b: pack W2 = W_attn[:, 256:768] into bf16 MFMA B-fragment layout.
// w2frag[(nt*16+kb)*64 + lane] (short8): h = nt*16+(lane&15),
// k = kb*32 + (lane>>4)*8 + j  (same k-map used for A fragments in k2).
__global__ __launch_bounds__(64) void k1b_w2frag(
    const float* __restrict__ W_attn, unsigned short* __restrict__ w2frag)
{
    const int blk = blockIdx.x;          // 0..255 = nt*16 + kb
    const int nt = blk >> 4, kb = blk & 15;
    const int l = threadIdx.x, lr = l & 15, lg = l >> 4;
    const int h = nt * 16 + lr;
    const float* src = W_attn + (size_t)h * K3H + Hn + kb * 32 + lg * 8;
    float4 x0 = *reinterpret_cast<const float4*>(src);
    float4 x1 = *reinterpret_cast<const float4*>(src + 4);
    short8 o;
    o[0] = (short)f2bf(x0.x); o[1] = (short)f2bf(x0.y);
    o[2] = (short)f2bf(x0.z); o[3] = (short)f2bf(x0.w);
    o[4] = (short)f2bf(x1.x); o[5] = (short)f2bf(x1.y);
    o[6] = (short)f2bf(x1.z); o[7] = (short)f2bf(x1.w);
    reinterpret_cast<short8*>(w2frag)[(size_t)blk * 64 + l] = o;
}

// K2: scores[tb] = sum_h v[h]*tanh(baseT[h][b] + sum_k enc[tb][k]*W2[h][k])
// MFMA GEMM: M-tile 128 rows (2 t's), N=256, K=512. 512 thr = 8 waves
// (4 M-waves x 2 N-waves; wave tile 32M x 128N). bf16 in, f32 acc.
__global__ __launch_bounds__(512, 2) void k2_scores(
    const float* __restrict__ enc, const unsigned short* __restrict__ w2frag,
    const float* __restrict__ vvec, const float* __restrict__ baseT,
    float* __restrict__ scores)
{
    const int tb0 = blockIdx.x * 128;
    const int l = threadIdx.x & 63;
    const int w = threadIdx.x >> 6;      // 0..7
    const int mw = w >> 1, nwv = w & 1;
    const int lr = l & 15, lg = l >> 4;  // frag row/col sel, k-group

    f32x4 acc[2][8];
    const f32x4 zero = {0.f, 0.f, 0.f, 0.f};
#pragma unroll
    for (int mi = 0; mi < 2; ++mi)
#pragma unroll
        for (int ni = 0; ni < 8; ++ni) acc[mi][ni] = zero;

    const short8* wf = reinterpret_cast<const short8*>(w2frag);

    for (int kb = 0; kb < 16; ++kb) {
        short8 a[2];
#pragma unroll
        for (int mi = 0; mi < 2; ++mi) {
            const float* src = enc + (size_t)(tb0 + mw * 32 + mi * 16 + lr) * D2H
                             + kb * 32 + lg * 8;
            float4 x0 = *reinterpret_cast<const float4*>(src);
            float4 x1 = *reinterpret_cast<const float4*>(src + 4);
            a[mi][0] = (short)f2bf(x0.x); a[mi][1] = (short)f2bf(x0.y);
            a[mi][2] = (short)f2bf(x0.z); a[mi][3] = (short)f2bf(x0.w);
            a[mi][4] = (short)f2bf(x1.x); a[mi][5] = (short)f2bf(x1.y);
            a[mi][6] = (short)f2bf(x1.z); a[mi][7] = (short)f2bf(x1.w);
        }
#pragma unroll
        for (int ni = 0; ni < 8; ++ni) {
            short8 bfr = wf[(size_t)(((nwv * 8 + ni) * 16) + kb) * 64 + l];
            acc[0][ni] = __builtin_amdgcn_mfma_f32_16x16x32_bf16(a[0], bfr, acc[0][ni], 0, 0, 0);
            acc[1][ni] = __builtin_amdgcn_mfma_f32_16x16x32_bf16(a[1], bfr, acc[1][ni], 0, 0, 0);
        }
    }

    // epilogue: psum[mi][reg] = sum_ni v[h]*tanh(acc + base)
    float psum[2][4] = {{0.f,0.f,0.f,0.f},{0.f,0.f,0.f,0.f}};
#pragma unroll
    for (int ni = 0; ni < 8; ++ni) {
        const int h = nwv * 128 + ni * 16 + lr;
        const float vh = vvec[h];
        const float* bt = baseT + h * Bn;
#pragma unroll
        for (int mi = 0; mi < 2; ++mi)
#pragma unroll
            for (int r = 0; r < 4; ++r) {
                const int rl = mw * 32 + mi * 16 + lg * 4 + r;   // local row
                const float e = acc[mi][ni][r] + bt[rl & 63];
                psum[mi][r] += vh * tanhf(e);
            }
    }

    __shared__ float red[128][32];
#pragma unroll
    for (int mi = 0; mi < 2; ++mi)
#pragma unroll
        for (int r = 0; r < 4; ++r)
            red[mw * 32 + mi * 16 + lg * 4 + r][nwv * 16 + lr] = psum[mi][r];
    __syncthreads();
    if (threadIdx.x < 128) {
        float s = 0.f;
#pragma unroll
        for (int c = 0; c < 32; ++c) s += red[threadIdx.x][c];
        scores[(size_t)tb0 + threadIdx.x] = s;
    }
}

// K3: in-place softmax over t (axis 0) for each b
__global__ __launch_bounds__(1024) void k3_softmax(float* __restrict__ sc)
{
    const int b = blockIdx.x;
    __shared__ float red[1024];
    float m = -1e30f;
    for (int t = threadIdx.x; t < Tn; t += 1024) m = fmaxf(m, sc[(size_t)t * Bn + b]);
    red[threadIdx.x] = m; __syncthreads();
    for (int s = 512; s > 0; s >>= 1) {
        if (threadIdx.x < s) red[threadIdx.x] = fmaxf(red[threadIdx.x], red[threadIdx.x + s]);
        __syncthreads();
    }
    m = red[0]; __syncthreads();
    float l = 0.f;
    for (int t = threadIdx.x; t < Tn; t += 1024) l += expf(sc[(size_t)t * Bn + b] - m);
    red[threadIdx.x] = l; __syncthreads();
    for (int s = 512; s > 0; s >>= 1) {
        if (threadIdx.x < s) red[threadIdx.x] += red[threadIdx.x + s];
        __syncthreads();
    }
    l = red[0];
    const float inv = 1.0f / l;
    for (int t = threadIdx.x; t < Tn; t += 1024) {
        size_t i = (size_t)t * Bn + b;
        sc[i] = expf(sc[i] - m) * inv;
    }
}

// K4: context partials over 32 chunks of 128 t
__global__ __launch_bounds__(256) void k4_ctx_part(
    const float* __restrict__ enc, const float* __restrict__ attn,
    float* __restrict__ part)
{
    const int tc = blockIdx.x, b = blockIdx.y, d = threadIdx.x;
    float c0 = 0.f, c1 = 0.f;
    for (int tt = 0; tt < 128; ++tt) {
        const int t = tc * 128 + tt;
        const float w = attn[(size_t)t * Bn + b];
        const float* e = enc + (size_t)t * (Bn * D2H) + b * D2H;
        c0 += w * e[d];
        c1 += w * e[d + 256];
    }
    float* p = part + ((size_t)tc * Bn + b) * D2H;
    p[d] = c0; p[d + 256] = c1;
}

// K5: reduce partials -> ctx, written into y[b][256:768]
__global__ __launch_bounds__(256) void k5_ctx_reduce(
    const float* __restrict__ part, float* __restrict__ y)
{
    const int b = blockIdx.x, d = threadIdx.x;
    float c0 = 0.f, c1 = 0.f;
    for (int tc = 0; tc < 32; ++tc) {
        const float* p = part + ((size_t)tc * Bn + b) * D2H;
        c0 += p[d]; c1 += p[d + 256];
    }
    y[(size_t)b * K3H + Hn + d] = c0;
    y[(size_t)b * K3H + Hn + 256 + d] = c1;
}

// K6: comb = W_comb @ [ctx, emb] + b_comb; GRU step -> h_new
__global__ __launch_bounds__(256) void k6_gru(
    const float* __restrict__ hidden, const float* __restrict__ emb_g,
    const float* __restrict__ W_comb, const float* __restrict__ b_comb,
    const float* __restrict__ W_ih, const float* __restrict__ W_hh,
    const float* __restrict__ b_ih, const float* __restrict__ b_hh,
    float* __restrict__ y, float* __restrict__ out_hidden)
{
    const int b = blockIdx.x, h = threadIdx.x;
    __shared__ float in_[K3H];
    __shared__ float h0[Hn];
    __shared__ float comb[Hn];
    __shared__ float gx[K3H], gh[K3H];
    in_[h]       = y[(size_t)b * K3H + Hn + h];
    in_[256 + h] = y[(size_t)b * K3H + Hn + 256 + h];
    in_[512 + h] = emb_g[b * En + h];
    h0[h] = hidden[b * Hn + h];
    __syncthreads();
    {
        float c = b_comb[h];
        const float* wr = W_comb + (size_t)h * K3H;
#pragma unroll 8
        for (int k = 0; k < K3H; ++k) c += wr[k] * in_[k];
        comb[h] = c;
    }
    __syncthreads();
#pragma unroll
    for (int p = 0; p < 3; ++p) {
        const int g = p * 256 + h;
        float a = b_ih[g], bh = b_hh[g];
        const float* wi = W_ih + (size_t)g * Hn;
        const float* wh = W_hh + (size_t)g * Hn;
#pragma unroll 8
        for (int k = 0; k < Hn; ++k) { a += wi[k] * comb[k]; bh += wh[k] * h0[k]; }
        gx[g] = a; gh[g] = bh;
    }
    __syncthreads();
    const float r = 1.f / (1.f + expf(-(gx[h] + gh[h])));
    const float z = 1.f / (1.f + expf(-(gx[256 + h] + gh[256 + h])));
    const float n = tanhf(gx[512 + h] + r * gh[512 + h]);
    const float hn = (1.f - z) * n + z * h0[h];
    y[(size_t)b * K3H + h] = hn;
    out_hidden[b * Hn + h] = hn;
}

// K7: logits[b][v] = b_out[v] + W_out[v] . y[b]
__global__ __launch_bounds__(256) void k7_logits(
    const float* __restrict__ W_out, const float* __restrict__ b_out,
    const float* __restrict__ y, float* __restrict__ out)
{
    const int vbase = blockIdx.x * 64;
    const int tv = threadIdx.x & 15;
    const int tb = threadIdx.x >> 4;
    __shared__ float lw[64][33];
    __shared__ float ly[32][68];
    float acc[4][4] = {};
    for (int kc = 0; kc < 24; ++kc) {
        __syncthreads();
#pragma unroll
        for (int u = 0; u < 8; ++u) {
            int idx = threadIdx.x + u * 256;
            int r = idx >> 5, c = idx & 31;
            int vv = vbase + r;
            lw[r][c] = (vv < Vn) ? W_out[(size_t)vv * K3H + kc * 32 + c] : 0.f;
        }
#pragma unroll
        for (int u = 0; u < 8; ++u) {
            int idx = threadIdx.x + u * 256;
            int k = idx >> 6, bb = idx & 63;
            ly[k][bb] = y[(size_t)bb * K3H + kc * 32 + k];
        }
        __syncthreads();
        for (int k = 0; k < 32; ++k) {
            float wv[4], yv[4];
#pragma unroll
            for (int i = 0; i < 4; ++i) wv[i] = lw[tv * 4 + i][k];
#pragma unroll
            for (int j = 0; j < 4; ++j) yv[j] = ly[k][tb * 4 + j];
#pragma unroll
            for (int i = 0; i < 4; ++i)
#pragma unroll
                for (int j = 0; j < 4; ++j) acc[i][j] += wv[i] * yv[j];
        }
    }
#pragma unroll
    for (int i = 0; i < 4; ++i) {
        const int vv = vbase + tv * 4 + i;
        if (vv < Vn) {
            const float bo = b_out[vv];
#pragma unroll
            for (int j = 0; j < 4; ++j) {
                const int b = tb * 4 + j;
                out[(size_t)b * Vn + vv] = acc[i][j] + bo;
            }
        }
    }
}

// K8: in-place log_softmax over V per row b
__global__ __launch_bounds__(1024) void k8_logsoftmax(float* __restrict__ out)
{
    const int b = blockIdx.x;
    float* row = out + (size_t)b * Vn;
    __shared__ float red[1024];
    float m = -1e30f;
    for (int i = threadIdx.x; i < Vn; i += 1024) m = fmaxf(m, row[i]);
    red[threadIdx.x] = m; __syncthreads();
    for (int s = 512; s > 0; s >>= 1) {
        if (threadIdx.x < s) red[threadIdx.x] = fmaxf(red[threadIdx.x], red[threadIdx.x + s]);
        __syncthreads();
    }
    m = red[0]; __syncthreads();
    float l = 0.f;
    for (int i = threadIdx.x; i < Vn; i += 1024) l += expf(row[i] - m);
    red[threadIdx.x] = l; __syncthreads();
    for (int s = 512; s > 0; s >>= 1) {
        if (threadIdx.x < s) red[threadIdx.x] += red[threadIdx.x + s];
        __syncthreads();
    }
    l = red[0];
    const float off = m + logf(l);
    for (int i = threadIdx.x; i < Vn; i += 1024) row[i] = row[i] - off;
}

extern "C" void kernel_launch(void* const* d_in, const int* in_sizes, int n_in,
                              void* d_out, int out_size, void* d_ws, size_t ws_size,
                              hipStream_t stream)
{
    const int*   ids    = (const int*)d_in[0];
    const float* hidden = (const float*)d_in[1];
    const float* enc    = (const float*)d_in[2];
    const float* emb    = (const float*)d_in[3];
    const float* W_attn = (const float*)d_in[4];
    const float* b_attn = (const float*)d_in[5];
    const float* vvec   = (const float*)d_in[6];
    const float* W_comb = (const float*)d_in[7];
    const float* b_comb = (const float*)d_in[8];
    const float* W_ih   = (const float*)d_in[9];
    const float* W_hh   = (const float*)d_in[10];
    const float* b_ih   = (const float*)d_in[11];
    const float* b_hh   = (const float*)d_in[12];
    const float* W_out  = (const float*)d_in[13];
    const float* b_out  = (const float*)d_in[14];

    float* out = (float*)d_out;
    float* ws = (float*)d_ws;
    float* baseT = ws;                        // 16384
    float* emb_g = ws + 16384;                // 16384
    float* attn  = ws + 32768;                // 262144
    float* part  = ws + 294912;               // 1048576
    float* y     = ws + 1343488;              // 49152
    unsigned short* w2frag = (unsigned short*)(ws + 1392640); // 131072 bf16

    hipLaunchKernelGGL(k1_embed_base, dim3(Bn), dim3(256), 0, stream,
                       ids, hidden, emb, W_attn, b_attn, baseT, emb_g);
    hipLaunchKernelGGL(k1b_w2frag, dim3(256), dim3(64), 0, stream,
                       W_attn, w2frag);
    hipLaunchKernelGGL(k2_scores, dim3(2048), dim3(512), 0, stream,
                       enc, w2frag, vvec, baseT, attn);
    hipLaunchKernelGGL(k3_softmax, dim3(Bn), dim3(1024), 0, stream, attn);
    hipLaunchKernelGGL(k4_ctx_part, dim3(32, Bn), dim3(256), 0, stream,
                       enc, attn, part);
    hipLaunchKernelGGL(k5_ctx_reduce, dim3(Bn), dim3(256), 0, stream, part, y);
    hipLaunchKernelGGL(k6_gru, dim3(Bn), dim3(256), 0, stream,
                       hidden, emb_g, W_comb, b_comb, W_ih, W_hh, b_ih, b_hh,
                       y, out + (size_t)Bn * Vn);
    hipLaunchKernelGGL(k7_logits, dim3((Vn + 63) / 64), dim3(256), 0, stream,
                       W_out, b_out, y, out);
    hipLaunchKernelGGL(k8_logsoftmax, dim3(Bn), dim3(1024), 0, stream, out);
}

// Round 3
// 778.769 us; speedup vs baseline: 21.6043x; 1.0293x over previous
//
#include <hip/hip_runtime.h>
#include <hip/hip_bf16.h>
#include <cstdint>
#include <cstddef>

#define Tn 4096
#define Bn 64
#define Hn 256
#define En 256
#define Vn 50257
#define D2H 512   // 2H
#define K3H 768   // 3H

typedef __attribute__((ext_vector_type(8))) short short8;
typedef __attribute__((ext_vector_type(4))) float f32x4;

__device__ __forceinline__ short bfs(float f)
{
    __hip_bfloat16 h = __float2bfloat16(f);   // RNE, lowers to v_cvt_pk_bf16_f32
    return *reinterpret_cast<short*>(&h);
}

__device__ __forceinline__ short8 pack8(const float4 x0, const float4 x1)
{
    short8 r;
    r[0] = bfs(x0.x); r[1] = bfs(x0.y); r[2] = bfs(x0.z); r[3] = bfs(x0.w);
    r[4] = bfs(x1.x); r[5] = bfs(x1.y); r[6] = bfs(x1.z); r[7] = bfs(x1.w);
    return r;
}

// ---------------------------------------------------------------------------
// ws layout (float offsets):
//   baseT  : [0, 16384)          (256h x 64b)
//   emb_g  : [16384, 32768)      (64b x 256e)
//   attn   : [32768, 294912)     (4096t x 64b)
//   part   : [294912, 1343488)   (32tc x 64b x 512d)
//   y      : [1343488, 1392640)  (64b x 768)
//   w2frag : [1392640, 1458176)  256 KB bf16 W2 fragments
// ---------------------------------------------------------------------------

__global__ __launch_bounds__(256) void k1_embed_base(
    const int* __restrict__ ids, const float* __restrict__ hidden,
    const float* __restrict__ emb, const float* __restrict__ W_attn,
    const float* __restrict__ b_attn,
    float* __restrict__ baseT, float* __restrict__ emb_g)
{
    const int b = blockIdx.x, h = threadIdx.x;
    __shared__ float h0[Hn];
    h0[h] = hidden[b * Hn + h];
    __syncthreads();
    float acc = b_attn[h];
    const float* wrow = W_attn + (size_t)h * K3H;
#pragma unroll 8
    for (int k = 0; k < Hn; ++k) acc += wrow[k] * h0[k];
    baseT[h * Bn + b] = acc;
    const int id = ids[b];
    emb_g[b * En + h] = emb[(size_t)id * En + h];
}

// K1b: pack W2 into bf16 MFMA B-fragment layout (unchanged layout).
__global__ __launch_bounds__(64) void k1b_w2frag(
    const float* __restrict__ W_attn, unsigned short* __restrict__ w2frag)
{
    const int blk = blockIdx.x;          // nt*16 + kb
    const int nt = blk >> 4, kb = blk & 15;
    const int l = threadIdx.x, lr = l & 15, lg = l >> 4;
    const int h = nt * 16 + lr;
    const float* src = W_attn + (size_t)h * K3H + Hn + kb * 32 + lg * 8;
    float4 x0 = *reinterpret_cast<const float4*>(src);
    float4 x1 = *reinterpret_cast<const float4*>(src + 4);
    reinterpret_cast<short8*>(w2frag)[(size_t)blk * 64 + l] = pack8(x0, x1);
}

// K2: MFMA GEMM, M-tile 256 rows/block, depth-1 SW pipeline on A loads.
// 512 thr = 8 waves = 4 M-waves (64 rows each) x 2 N-waves (128 h each).
__global__ __launch_bounds__(512, 2) void k2_scores(
    const float* __restrict__ enc, const unsigned short* __restrict__ w2frag,
    const float* __restrict__ vvec, const float* __restrict__ baseT,
    float* __restrict__ scores)
{
    const int tb0 = blockIdx.x * 256;
    const int l = threadIdx.x & 63;
    const int w = threadIdx.x >> 6;      // 0..7
    const int mw = w >> 1, nwv = w & 1;
    const int lr = l & 15, lg = l >> 4;

    f32x4 acc[4][8];
    const f32x4 zero = {0.f, 0.f, 0.f, 0.f};
#pragma unroll
    for (int mi = 0; mi < 4; ++mi)
#pragma unroll
        for (int ni = 0; ni < 8; ++ni) acc[mi][ni] = zero;

    const short8* wf = reinterpret_cast<const short8*>(w2frag);

    // per-mi base pointers (k-offset folds into imm)
    const float* arow[4];
#pragma unroll
    for (int mi = 0; mi < 4; ++mi)
        arow[mi] = enc + (size_t)(tb0 + mw * 64 + mi * 16 + lr) * D2H + lg * 8;

#define LOADA(dst, kk) do {                                                  \
    const int _k = (kk) < 15 ? (kk) : 15;                                    \
    _Pragma("unroll")                                                        \
    for (int mi = 0; mi < 4; ++mi) {                                         \
        const float4* p = reinterpret_cast<const float4*>(arow[mi] + _k*32); \
        dst[mi][0] = p[0]; dst[mi][1] = p[1];                                \
    } } while (0)

#define PROCESS(buf, kb) do {                                                \
    short8 bfr[8];                                                           \
    _Pragma("unroll")                                                        \
    for (int ni = 0; ni < 8; ++ni)                                           \
        bfr[ni] = wf[(size_t)(((nwv * 8 + ni) * 16) + (kb)) * 64 + l];       \
    _Pragma("unroll")                                                        \
    for (int mi = 0; mi < 4; ++mi) {                                         \
        short8 a = pack8(buf[mi][0], buf[mi][1]);                            \
        _Pragma("unroll")                                                    \
        for (int ni = 0; ni < 8; ++ni)                                       \
            acc[mi][ni] = __builtin_amdgcn_mfma_f32_16x16x32_bf16(           \
                a, bfr[ni], acc[mi][ni], 0, 0, 0);                           \
    } } while (0)

    float4 A0[4][2], A1[4][2];
    LOADA(A0, 0);
#pragma unroll
    for (int kb = 0; kb < 16; kb += 2) {
        LOADA(A1, kb + 1);
        PROCESS(A0, kb);
        if (kb + 2 < 16) LOADA(A0, kb + 2);
        PROCESS(A1, kb + 1);
    }
#undef LOADA
#undef PROCESS

    // epilogue: psum[mi][r] = sum_ni v[h]*tanh(acc + base); b = mi*16+lg*4+r
    float psum[4][4];
#pragma unroll
    for (int mi = 0; mi < 4; ++mi)
#pragma unroll
        for (int r = 0; r < 4; ++r) psum[mi][r] = 0.f;
#pragma unroll
    for (int ni = 0; ni < 8; ++ni) {
        const int h = nwv * 128 + ni * 16 + lr;
        const float vh = vvec[h];
        const float* bt = baseT + h * Bn;
#pragma unroll
        for (int mi = 0; mi < 4; ++mi)
#pragma unroll
            for (int r = 0; r < 4; ++r) {
                const int b = mi * 16 + lg * 4 + r;     // row & 63
                const float e = acc[mi][ni][r] + bt[b];
                psum[mi][r] += vh * tanhf(e);
            }
    }

    __shared__ float red[256][33];
#pragma unroll
    for (int mi = 0; mi < 4; ++mi)
#pragma unroll
        for (int r = 0; r < 4; ++r)
            red[mw * 64 + mi * 16 + lg * 4 + r][nwv * 16 + lr] = psum[mi][r];
    __syncthreads();
    if (threadIdx.x < 256) {
        float s = 0.f;
#pragma unroll
        for (int c = 0; c < 32; ++c) s += red[threadIdx.x][c];
        scores[(size_t)tb0 + threadIdx.x] = s;
    }
}

// K3: softmax over t for each b
__global__ __launch_bounds__(1024) void k3_softmax(float* __restrict__ sc)
{
    const int b = blockIdx.x;
    __shared__ float red[1024];
    float m = -1e30f;
    for (int t = threadIdx.x; t < Tn; t += 1024) m = fmaxf(m, sc[(size_t)t * Bn + b]);
    red[threadIdx.x] = m; __syncthreads();
    for (int s = 512; s > 0; s >>= 1) {
        if (threadIdx.x < s) red[threadIdx.x] = fmaxf(red[threadIdx.x], red[threadIdx.x + s]);
        __syncthreads();
    }
    m = red[0]; __syncthreads();
    float l = 0.f;
    for (int t = threadIdx.x; t < Tn; t += 1024) l += expf(sc[(size_t)t * Bn + b] - m);
    red[threadIdx.x] = l; __syncthreads();
    for (int s = 512; s > 0; s >>= 1) {
        if (threadIdx.x < s) red[threadIdx.x] += red[threadIdx.x + s];
        __syncthreads();
    }
    l = red[0];
    const float inv = 1.0f / l;
    for (int t = threadIdx.x; t < Tn; t += 1024) {
        size_t i = (size_t)t * Bn + b;
        sc[i] = expf(sc[i] - m) * inv;
    }
}

// K4: context partials, float2 + 4-way ILP
__global__ __launch_bounds__(256) void k4_ctx_part(
    const float* __restrict__ enc, const float* __restrict__ attn,
    float* __restrict__ part)
{
    const int tc = blockIdx.x, b = blockIdx.y, tid = threadIdx.x;
    const float* aw = attn + (size_t)tc * 128 * Bn + b;
    float2 s0 = {0.f, 0.f}, s1 = {0.f, 0.f}, s2 = {0.f, 0.f}, s3 = {0.f, 0.f};
#pragma unroll 4
    for (int tt = 0; tt < 128; tt += 4) {
        const float w0 = aw[(tt + 0) * Bn];
        const float w1 = aw[(tt + 1) * Bn];
        const float w2 = aw[(tt + 2) * Bn];
        const float w3 = aw[(tt + 3) * Bn];
        const float* e0 = enc + (size_t)(tc * 128 + tt) * (Bn * D2H) + b * D2H;
        const float2 v0 = reinterpret_cast<const float2*>(e0)[tid];
        const float2 v1 = reinterpret_cast<const float2*>(e0 + Bn * D2H)[tid];
        const float2 v2 = reinterpret_cast<const float2*>(e0 + 2 * Bn * D2H)[tid];
        const float2 v3 = reinterpret_cast<const float2*>(e0 + 3 * Bn * D2H)[tid];
        s0.x += w0 * v0.x; s0.y += w0 * v0.y;
        s1.x += w1 * v1.x; s1.y += w1 * v1.y;
        s2.x += w2 * v2.x; s2.y += w2 * v2.y;
        s3.x += w3 * v3.x; s3.y += w3 * v3.y;
    }
    float2 r;
    r.x = (s0.x + s1.x) + (s2.x + s3.x);
    r.y = (s0.y + s1.y) + (s2.y + s3.y);
    reinterpret_cast<float2*>(part + ((size_t)tc * Bn + b) * D2H)[tid] = r;
}

// K5: reduce partials -> ctx into y[b][256:768]
__global__ __launch_bounds__(256) void k5_ctx_reduce(
    const float* __restrict__ part, float* __restrict__ y)
{
    const int b = blockIdx.x, d = threadIdx.x;
    float c0 = 0.f, c1 = 0.f;
    for (int tc = 0; tc < 32; ++tc) {
        const float* p = part + ((size_t)tc * Bn + b) * D2H;
        c0 += p[d]; c1 += p[d + 256];
    }
    y[(size_t)b * K3H + Hn + d] = c0;
    y[(size_t)b * K3H + Hn + 256 + d] = c1;
}

// K6: combine + GRU
__global__ __launch_bounds__(256) void k6_gru(
    const float* __restrict__ hidden, const float* __restrict__ emb_g,
    const float* __restrict__ W_comb, const float* __restrict__ b_comb,
    const float* __restrict__ W_ih, const float* __restrict__ W_hh,
    const float* __restrict__ b_ih, const float* __restrict__ b_hh,
    float* __restrict__ y, float* __restrict__ out_hidden)
{
    const int b = blockIdx.x, h = threadIdx.x;
    __shared__ float in_[K3H];
    __shared__ float h0[Hn];
    __shared__ float comb[Hn];
    __shared__ float gx[K3H], gh[K3H];
    in_[h]       = y[(size_t)b * K3H + Hn + h];
    in_[256 + h] = y[(size_t)b * K3H + Hn + 256 + h];
    in_[512 + h] = emb_g[b * En + h];
    h0[h] = hidden[b * Hn + h];
    __syncthreads();
    {
        float c = b_comb[h];
        const float* wr = W_comb + (size_t)h * K3H;
#pragma unroll 8
        for (int k = 0; k < K3H; ++k) c += wr[k] * in_[k];
        comb[h] = c;
    }
    __syncthreads();
#pragma unroll
    for (int p = 0; p < 3; ++p) {
        const int g = p * 256 + h;
        float a = b_ih[g], bh = b_hh[g];
        const float* wi = W_ih + (size_t)g * Hn;
        const float* wh = W_hh + (size_t)g * Hn;
#pragma unroll 8
        for (int k = 0; k < Hn; ++k) { a += wi[k] * comb[k]; bh += wh[k] * h0[k]; }
        gx[g] = a; gh[g] = bh;
    }
    __syncthreads();
    const float r = 1.f / (1.f + expf(-(gx[h] + gh[h])));
    const float z = 1.f / (1.f + expf(-(gx[256 + h] + gh[256 + h])));
    const float n = tanhf(gx[512 + h] + r * gh[512 + h]);
    const float hn = (1.f - z) * n + z * h0[h];
    y[(size_t)b * K3H + h] = hn;
    out_hidden[b * Hn + h] = hn;
}

// K7: logits GEMM (64v x 64b tiles)
__global__ __launch_bounds__(256) void k7_logits(
    const float* __restrict__ W_out, const float* __restrict__ b_out,
    const float* __restrict__ y, float* __restrict__ out)
{
    const int vbase = blockIdx.x * 64;
    const int tv = threadIdx.x & 15;
    const int tb = threadIdx.x >> 4;
    __shared__ float lw[64][33];
    __shared__ float ly[32][68];
    float acc[4][4] = {};
    for (int kc = 0; kc < 24; ++kc) {
        __syncthreads();
#pragma unroll
        for (int u = 0; u < 8; ++u) {
            int idx = threadIdx.x + u * 256;
            int r = idx >> 5, c = idx & 31;
            int vv = vbase + r;
            lw[r][c] = (vv < Vn) ? W_out[(size_t)vv * K3H + kc * 32 + c] : 0.f;
        }
#pragma unroll
        for (int u = 0; u < 8; ++u) {
            int idx = threadIdx.x + u * 256;
            int k = idx >> 6, bb = idx & 63;
            ly[k][bb] = y[(size_t)bb * K3H + kc * 32 + k];
        }
        __syncthreads();
        for (int k = 0; k < 32; ++k) {
            float wv[4], yv[4];
#pragma unroll
            for (int i = 0; i < 4; ++i) wv[i] = lw[tv * 4 + i][k];
#pragma unroll
            for (int j = 0; j < 4; ++j) yv[j] = ly[k][tb * 4 + j];
#pragma unroll
            for (int i = 0; i < 4; ++i)
#pragma unroll
                for (int j = 0; j < 4; ++j) acc[i][j] += wv[i] * yv[j];
        }
    }
#pragma unroll
    for (int i = 0; i < 4; ++i) {
        const int vv = vbase + tv * 4 + i;
        if (vv < Vn) {
            const float bo = b_out[vv];
#pragma unroll
            for (int j = 0; j < 4; ++j) {
                const int b = tb * 4 + j;
                out[(size_t)b * Vn + vv] = acc[i][j] + bo;
            }
        }
    }
}

// K8: log_softmax over V per row
__global__ __launch_bounds__(1024) void k8_logsoftmax(float* __restrict__ out)
{
    const int b = blockIdx.x;
    float* row = out + (size_t)b * Vn;
    __shared__ float red[1024];
    float m = -1e30f;
    for (int i = threadIdx.x; i < Vn; i += 1024) m = fmaxf(m, row[i]);
    red[threadIdx.x] = m; __syncthreads();
    for (int s = 512; s > 0; s >>= 1) {
        if (threadIdx.x < s) red[threadIdx.x] = fmaxf(red[threadIdx.x], red[threadIdx.x + s]);
        __syncthreads();
    }
    m = red[0]; __syncthreads();
    float l = 0.f;
    for (int i = threadIdx.x; i < Vn; i += 1024) l += expf(row[i] - m);
    red[threadIdx.x] = l; __syncthreads();
    for (int s = 512; s > 0; s >>= 1) {
        if (threadIdx.x < s) red[threadIdx.x] += red[threadIdx.x + s];
        __syncthreads();
    }
    l = red[0];
    const float off = m + logf(l);
    for (int i = threadIdx.x; i < Vn; i += 1024) row[i] = row[i] - off;
}

extern "C" void kernel_launch(void* const* d_in, const int* in_sizes, int n_in,
                              void* d_out, int out_size, void* d_ws, size_t ws_size,
                              hipStream_t stream)
{
    const int*   ids    = (const int*)d_in[0];
    const float* hidden = (const float*)d_in[1];
    const float* enc    = (const float*)d_in[2];
    const float* emb    = (const float*)d_in[3];
    const float* W_attn = (const float*)d_in[4];
    const float* b_attn = (const float*)d_in[5];
    const float* vvec   = (const float*)d_in[6];
    const float* W_comb = (const float*)d_in[7];
    const float* b_comb = (const float*)d_in[8];
    const float* W_ih   = (const float*)d_in[9];
    const float* W_hh   = (const float*)d_in[10];
    const float* b_ih   = (const float*)d_in[11];
    const float* b_hh   = (const float*)d_in[12];
    const float* W_out  = (const float*)d_in[13];
    const float* b_out  = (const float*)d_in[14];

    float* out = (float*)d_out;
    float* ws = (float*)d_ws;
    float* baseT = ws;                        // 16384
    float* emb_g = ws + 16384;                // 16384
    float* attn  = ws + 32768;                // 262144
    float* part  = ws + 294912;               // 1048576
    float* y     = ws + 1343488;              // 49152
    unsigned short* w2frag = (unsigned short*)(ws + 1392640); // 131072 bf16

    hipLaunchKernelGGL(k1_embed_base, dim3(Bn), dim3(256), 0, stream,
                       ids, hidden, emb, W_attn, b_attn, baseT, emb_g);
    hipLaunchKernelGGL(k1b_w2frag, dim3(256), dim3(64), 0, stream,
                       W_attn, w2frag);
    hipLaunchKernelGGL(k2_scores, dim3(1024), dim3(512), 0, stream,
                       enc, w2frag, vvec, baseT, attn);
    hipLaunchKernelGGL(k3_softmax, dim3(Bn), dim3(1024), 0, stream, attn);
    hipLaunchKernelGGL(k4_ctx_part, dim3(32, Bn), dim3(256), 0, stream,
                       enc, attn, part);
    hipLaunchKernelGGL(k5_ctx_reduce, dim3(Bn), dim3(256), 0, stream, part, y);
    hipLaunchKernelGGL(k6_gru, dim3(Bn), dim3(256), 0, stream,
                       hidden, emb_g, W_comb, b_comb, W_ih, W_hh, b_ih, b_hh,
                       y, out + (size_t)Bn * Vn);
    hipLaunchKernelGGL(k7_logits, dim3((Vn + 63) / 64), dim3(256), 0, stream,
                       W_out, b_out, y, out);
    hipLaunchKernelGGL(k8_logsoftmax, dim3(Bn), dim3(1024), 0, stream, out);
}